// Round 9
// baseline (113.853 us; speedup 1.0000x reference)
//
#include <hip/hip_runtime.h>

// Problem constants (fixed by the reference)
#define B_TOT 16384
#define TBB   16        // batch rows per block
#define NTH   512       // 8 waves; wave wv handles n in [4wv, 4wv+4)
#define SLS   524       // f32 stride of sL row (verified R2/R4/R5/R6/R8)

typedef short bf16x8 __attribute__((ext_vector_type(8)));
typedef float f32x4  __attribute__((ext_vector_type(4)));
union U4 { bf16x8 v; uint4 q; };

__device__ __forceinline__ unsigned f2bf(float f) {
    unsigned u = __float_as_uint(f);
    return (u + 0x7fffu + ((u >> 16) & 1u)) >> 16;   // RNE
}
__device__ __forceinline__ unsigned cvtpk(float lo, float hi) {   // bf16(lo) | bf16(hi)<<16
    unsigned r;
    asm("v_cvt_pk_bf16_f32 %0, %1, %2" : "=v"(r) : "v"(lo), "v"(hi));
    return r;
}

__device__ __forceinline__ uint4 packrow(const float* src) {   // 8 W elems, i-stride 16
    uint4 o;
    o.x = f2bf(src[0])  | (f2bf(src[16])  << 16);
    o.y = f2bf(src[32]) | (f2bf(src[48])  << 16);
    o.z = f2bf(src[64]) | (f2bf(src[80])  << 16);
    o.w = f2bf(src[96]) | (f2bf(src[112]) << 16);
    return o;
}
__device__ __forceinline__ uint4 packrow8(const float* src, float sc) {  // 8 contiguous, scaled
    uint4 o;
    o.x = f2bf(sc * src[0]) | (f2bf(sc * src[1]) << 16);
    o.y = f2bf(sc * src[2]) | (f2bf(sc * src[3]) << 16);
    o.z = f2bf(sc * src[4]) | (f2bf(sc * src[5]) << 16);
    o.w = f2bf(sc * src[6]) | (f2bf(sc * src[7]) << 16);
    return o;
}

// Workspace (uint4 units):
//  [0,8192):      Wk[n][s][lane] — K=32 A-frag (VERIFIED R4-R8): lane (q=l>>4, z=l&15)
//                 holds W[n][4s+q][i=0..7][z]. A row = lane&15, K-octet = lane>>4.
//  [8192,24576):  Wv[n][m][lane] — v-matmul A-frag: lane (g=l>>4, r=l&15) holds
//                 0.25*W[n][flat=16m+r -> j=2m+(r>>3), i=r&7][z=8g..8g+7] for g<2,
//                 ZERO for g>=2 (zeros-in-A masking = verified side; kills K=16..31).
__global__ void prepack(const float* __restrict__ W, uint4* __restrict__ Wp)
{
    const int t = blockIdx.x * 256 + threadIdx.x;   // 24576 threads
    if (t < 8192) {
        const int lane = t & 63, s = (t >> 6) & 3, n = t >> 8;
        const int q = lane >> 4, z = lane & 15;
        Wp[t] = packrow(W + (size_t)(n * 16 + 4 * s + q) * 128 + z);
    } else {
        const int u = t - 8192;
        const int lane = u & 63, m = (u >> 6) & 7, n = u >> 9;
        const int g = lane >> 4, r = lane & 15;
        const int j = 2 * m + (r >> 3), i = r & 7;
        uint4 o = make_uint4(0u, 0u, 0u, 0u);
        if (g < 2)
            o = packrow8(W + (size_t)((n * 16 + j) * 8 + i) * 16 + 8 * g, 0.25f);
        Wp[t] = o;
    }
}

// D-mapping (m89-verified, used by all passing rounds): col = lane&15 = b, row = 4*(l>>4)+reg.
// R7 lesson: never mask the B operand by lane-quarter; zeros must live on the A side.
__global__ __launch_bounds__(NTH, 4)
void caps(const float* __restrict__ X, const uint4* __restrict__ Wp,
          const float* __restrict__ Bias, float* __restrict__ Out)
{
    __shared__ __align__(16) float sL[TBB * SLS];   // logits -> c+bias, f32 (33.5 KB)
    __shared__ float sBias[512];

    const int t    = threadIdx.x;
    const int lane = t & 63;
    const int wv   = t >> 6;          // 0..7
    const int b16  = lane & 15;       // D col = batch row
    const int q    = lane >> 4;       // lane quarter
    const long bb  = (long)blockIdx.x * TBB;

    sBias[t] = Bias[t];

    // x B-frags (VERIFIED): frag s, lane (q,b16) = bf16 x[b16][4s+q][0..7]
    const float* xr = X + (bb + b16) * 128;
    uint4 xq[4];
    #pragma unroll
    for (int s = 0; s < 4; ++s) {
        const float* xs = xr + (4 * s + q) * 8;
        float4 a = *reinterpret_cast<const float4*>(xs);
        float4 c = *reinterpret_cast<const float4*>(xs + 4);
        uint4 o;
        o.x = f2bf(a.x) | (f2bf(a.y) << 16);
        o.y = f2bf(a.z) | (f2bf(a.w) << 16);
        o.z = f2bf(c.x) | (f2bf(c.y) << 16);
        o.w = f2bf(c.z) | (f2bf(c.w) << 16);
        xq[s] = o;
    }

    // pass-1 dot x values (raw f32): x1[m] = x[b16][j=2m+(q>>1)][i=4(q&1)..+3]
    float4 x1[8];
    #pragma unroll
    for (int m = 0; m < 8; ++m)
        x1[m] = *reinterpret_cast<const float4*>(xr + (2 * m + (q >> 1)) * 8 + 4 * (q & 1));

    const f32x4 zero4 = {0.f, 0.f, 0.f, 0.f};
    uint4 wk[4];

    // ---------------- pass 1: logits via v-matmul ----------------
    #pragma unroll 1
    for (int nq = 0; nq < 4; ++nq) {
        const int n = wv * 4 + nq;
        const uint4* pw = Wp + n * 256 + lane;
        wk[0] = pw[0]; wk[1] = pw[64]; wk[2] = pw[128]; wk[3] = pw[192];

        // usum[b,z]: 4 chained MFMAs (VERIFIED path). D: lane (q,b16) reg r = z=4q+r.
        f32x4 usum = zero4;
        #pragma unroll
        for (int s = 0; s < 4; ++s) {
            U4 a;  a.q  = wk[s];
            U4 xb; xb.q = xq[s];
            usum = __builtin_amdgcn_mfma_f32_16x16x32_bf16(a.v, xb.v, usum, 0, 0, 0);
        }

        // B-frag ub for v-matmul: lane q=0 needs z=0..7 (quads 0,1), q=1 z=8..15
        // (quads 2,3); q>=2 don't-care (A zero there). Quad Q lives at lane Q*16+b16.
        const int sA = ((2 * q) & 3) * 16 + b16;
        const int sB = ((2 * q + 1) & 3) * 16 + b16;
        const float qa0 = __shfl(usum[0], sA), qa1 = __shfl(usum[1], sA);
        const float qa2 = __shfl(usum[2], sA), qa3 = __shfl(usum[3], sA);
        const float qb0 = __shfl(usum[0], sB), qb1 = __shfl(usum[1], sB);
        const float qb2 = __shfl(usum[2], sB), qb3 = __shfl(usum[3], sB);
        U4 ub;
        ub.q.x = cvtpk(qa0, qa1); ub.q.y = cvtpk(qa2, qa3);
        ub.q.z = cvtpk(qb0, qb1); ub.q.w = cvtpk(qb2, qb3);

        // v[b, flat] = 0.25 * W . usum  (scale baked into Wv); then
        // logit[b, j=2m+(q>>1)] = sum_i x*v: 4 FMA + 1 shfl per m.
        const uint4* pv = Wp + 8192 + n * 512 + lane;
        #pragma unroll
        for (int m = 0; m < 8; ++m) {
            U4 a; a.q = pv[m * 64];
            f32x4 vd = __builtin_amdgcn_mfma_f32_16x16x32_bf16(a.v, ub.v, zero4, 0, 0, 0);
            float pm = vd[0] * x1[m].x;
            pm = fmaf(vd[1], x1[m].y, pm);
            pm = fmaf(vd[2], x1[m].z, pm);
            pm = fmaf(vd[3], x1[m].w, pm);
            pm += __shfl_xor(pm, 16);          // join the two i-halves (q^1)
            if (!(q & 1)) sL[b16 * SLS + n * 16 + 2 * m + (q >> 1)] = pm;
        }
    }
    __syncthreads();

    // ---------------- softmax over n (+ bias), one (b,j) per thread (VERIFIED) ----------------
    if (t < 256) {
        const int sb = t >> 4, sj = t & 15;
        float l[32];
        #pragma unroll
        for (int n = 0; n < 32; ++n) l[n] = sL[sb * SLS + n * 16 + sj];
        float m = l[0];
        #pragma unroll
        for (int n = 1; n < 32; ++n) m = fmaxf(m, l[n]);
        float Z = 0.f;
        #pragma unroll
        for (int n = 0; n < 32; ++n) { l[n] = __expf(l[n] - m); Z += l[n]; }
        const float inv = 1.0f / Z;
        #pragma unroll
        for (int n = 0; n < 32; ++n)
            sL[sb * SLS + n * 16 + sj] = fmaf(l[n], inv, sBias[n * 16 + sj]);
    }
    __syncthreads();

    // ---------------- pass 2: s[b,n,z] via c-folded B operand ----------------
    // s[b,n,:] = sum_{j,i} (c[b,j]*x[b,j,i]) * W[n,(j,i),:] — 4 chained MFMAs on
    // the VERIFIED Wk A-frags; y[s] = bf16(c * x) built in the verified xq layout.
    #pragma unroll 1
    for (int nq = 0; nq < 4; ++nq) {
        const int n = wv * 4 + nq;
        const uint4* pw = Wp + n * 256 + lane;
        wk[0] = pw[0]; wk[1] = pw[64]; wk[2] = pw[128]; wk[3] = pw[192];

        f32x4 sacc = zero4;
        #pragma unroll
        for (int s = 0; s < 4; ++s) {
            const float c = sL[b16 * SLS + n * 16 + 4 * s + q];   // c[b16][n][j=4s+q]
            const uint4 xv = xq[s];
            U4 y;
            y.q.x = cvtpk(c * __uint_as_float(xv.x << 16), c * __uint_as_float(xv.x & 0xffff0000u));
            y.q.y = cvtpk(c * __uint_as_float(xv.y << 16), c * __uint_as_float(xv.y & 0xffff0000u));
            y.q.z = cvtpk(c * __uint_as_float(xv.z << 16), c * __uint_as_float(xv.z & 0xffff0000u));
            y.q.w = cvtpk(c * __uint_as_float(xv.w << 16), c * __uint_as_float(xv.w & 0xffff0000u));
            U4 a; a.q = wk[s];
            sacc = __builtin_amdgcn_mfma_f32_16x16x32_bf16(a.v, y.v, sacc, 0, 0, 0);
        }
        // lane (b16, q) -> Out[bb+b16][n][4q .. 4q+3]  (VERIFIED epilogue)
        float4* op = reinterpret_cast<float4*>(Out + (bb + b16) * 512 + n * 16 + q * 4);
        *op = make_float4(sacc[0], sacc[1], sacc[2], sacc[3]);
    }
}

extern "C" void kernel_launch(void* const* d_in, const int* in_sizes, int n_in,
                              void* d_out, int out_size, void* d_ws, size_t ws_size,
                              hipStream_t stream) {
    const float* X  = (const float*)d_in[0];   // (16384, 16, 8) fp32
    const float* W  = (const float*)d_in[1];   // (32, 16, 8, 16) fp32
    const float* Bi = (const float*)d_in[2];   // (32, 16, 1) fp32
    float* Out = (float*)d_out;                // (16384, 32, 16) fp32

    uint4* Wp = (uint4*)d_ws;                  // 384 KiB packed fragments (Wk + Wv)
    prepack<<<96, 256, 0, stream>>>(W, Wp);
    caps<<<B_TOT / TBB, NTH, 0, stream>>>(X, Wp, Bi, Out);
}

// Round 10
// 110.887 us; speedup vs baseline: 1.0267x; 1.0267x over previous
//
#include <hip/hip_runtime.h>

// Problem constants (fixed by the reference)
#define B_TOT 16384
#define TBB   16        // batch rows per block
#define NTH   512       // 8 waves; wave wv handles n in [4wv, 4wv+4)
#define SLS   524       // f32 stride of sL row (verified R2-R9)
#define USR   20        // sUs row stride (floats; padded vs 16 to spread banks)

typedef short bf16x8 __attribute__((ext_vector_type(8)));
typedef float f32x4  __attribute__((ext_vector_type(4)));
union U4 { bf16x8 v; uint4 q; };

__device__ __forceinline__ unsigned f2bf(float f) {
    unsigned u = __float_as_uint(f);
    return (u + 0x7fffu + ((u >> 16) & 1u)) >> 16;   // RNE
}
__device__ __forceinline__ unsigned cvtpk(float lo, float hi) {   // bf16(lo) | bf16(hi)<<16
    unsigned r;
    asm("v_cvt_pk_bf16_f32 %0, %1, %2" : "=v"(r) : "v"(lo), "v"(hi));
    return r;
}

__device__ __forceinline__ uint4 packrow(const float* src) {   // 8 W elems, i-stride 16
    uint4 o;
    o.x = f2bf(src[0])  | (f2bf(src[16])  << 16);
    o.y = f2bf(src[32]) | (f2bf(src[48])  << 16);
    o.z = f2bf(src[64]) | (f2bf(src[80])  << 16);
    o.w = f2bf(src[96]) | (f2bf(src[112]) << 16);
    return o;
}
__device__ __forceinline__ uint4 packrow8(const float* src, float sc) {  // 8 contiguous, scaled
    uint4 o;
    o.x = f2bf(sc * src[0]) | (f2bf(sc * src[1]) << 16);
    o.y = f2bf(sc * src[2]) | (f2bf(sc * src[3]) << 16);
    o.z = f2bf(sc * src[4]) | (f2bf(sc * src[5]) << 16);
    o.w = f2bf(sc * src[6]) | (f2bf(sc * src[7]) << 16);
    return o;
}

// Workspace layout (uint4 units) — IDENTICAL to the R9-verified prepack:
//  [0,8192):      Wk[n][s][lane] — K=32 A-frag: lane (q=l>>4, z=l&15) holds
//                 W[n][4s+q][i=0..7][z].
//  [8192,24576):  Wv[n][m][lane] — v-matmul A-frag: lane (g=l>>4, r=l&15) holds
//                 0.25*W[n][j=2m+(r>>3), i=r&7][z=8g..8g+7] for g<2, ZERO for g>=2.
__global__ void prepack(const float* __restrict__ W, uint4* __restrict__ Wp)
{
    const int t = blockIdx.x * 256 + threadIdx.x;   // 24576 threads
    if (t < 8192) {
        const int lane = t & 63, s = (t >> 6) & 3, n = t >> 8;
        const int q = lane >> 4, z = lane & 15;
        Wp[t] = packrow(W + (size_t)(n * 16 + 4 * s + q) * 128 + z);
    } else {
        const int u = t - 8192;
        const int lane = u & 63, m = (u >> 6) & 7, n = u >> 9;
        const int g = lane >> 4, r = lane & 15;
        const int j = 2 * m + (r >> 3), i = r & 7;
        uint4 o = make_uint4(0u, 0u, 0u, 0u);
        if (g < 2)
            o = packrow8(W + (size_t)((n * 16 + j) * 8 + i) * 16 + 8 * g, 0.25f);
        Wp[t] = o;
    }
}

// D-mapping (m89-verified): col = lane&15 = b, row = 4*(l>>4)+reg.
// R7 lesson: zeros only on the A side. R10: bpermute -> per-wave LDS exchange
// (bit-identical f32), and 2-way n-interleave for in-wave latency hiding.
__global__ __launch_bounds__(NTH, 4)
void caps(const float* __restrict__ X, const uint4* __restrict__ Wp,
          const float* __restrict__ Bias, float* __restrict__ Out)
{
    __shared__ __align__(16) float sL[TBB * SLS];          // logits -> c+bias (33.5 KB)
    __shared__ __align__(16) float sUs[8 * 2 * 16 * USR];  // per-wave usum scratch (20 KB)
    __shared__ float sBias[512];

    const int t    = threadIdx.x;
    const int lane = t & 63;
    const int wv   = t >> 6;          // 0..7
    const int b16  = lane & 15;       // D col = batch row
    const int q    = lane >> 4;       // lane quarter
    const long bb  = (long)blockIdx.x * TBB;

    sBias[t] = Bias[t];

    // x B-frags (VERIFIED layout): frag s, lane (q,b16) = bf16 x[b16][4s+q][0..7]
    const float* xr = X + (bb + b16) * 128;
    uint4 xq[4];
    #pragma unroll
    for (int s = 0; s < 4; ++s) {
        const float* xs = xr + (4 * s + q) * 8;
        float4 a = *reinterpret_cast<const float4*>(xs);
        float4 c = *reinterpret_cast<const float4*>(xs + 4);
        uint4 o;
        o.x = f2bf(a.x) | (f2bf(a.y) << 16);
        o.y = f2bf(a.z) | (f2bf(a.w) << 16);
        o.z = f2bf(c.x) | (f2bf(c.y) << 16);
        o.w = f2bf(c.z) | (f2bf(c.w) << 16);
        xq[s] = o;
    }

    // pass-1 dot x values (raw f32): x1[m] = x[b16][j=2m+(q>>1)][i=4(q&1)..+3]
    float4 x1[8];
    #pragma unroll
    for (int m = 0; m < 8; ++m)
        x1[m] = *reinterpret_cast<const float4*>(xr + (2 * m + (q >> 1)) * 8 + 4 * (q & 1));

    const f32x4 zero4 = {0.f, 0.f, 0.f, 0.f};
    float* const usA = &sUs[((wv * 2 + 0) * 16 + b16) * USR];
    float* const usB = &sUs[((wv * 2 + 1) * 16 + b16) * USR];
    const int zo = 8 * (q & 1);       // z-octet this lane supplies as B K-octet

    // ---------------- pass 1: logits, 2 n in flight ----------------
    #pragma unroll 1
    for (int pr = 0; pr < 2; ++pr) {
        const int n0 = wv * 4 + 2 * pr, n1 = n0 + 1;
        const uint4* pw0 = Wp + n0 * 256 + lane;
        const uint4* pw1 = Wp + n1 * 256 + lane;
        uint4 wkA[4], wkB[4];
        wkA[0] = pw0[0]; wkA[1] = pw0[64]; wkA[2] = pw0[128]; wkA[3] = pw0[192];
        wkB[0] = pw1[0]; wkB[1] = pw1[64]; wkB[2] = pw1[128]; wkB[3] = pw1[192];

        // two independent usum chains (VERIFIED path)
        f32x4 uA = zero4, uB = zero4;
        #pragma unroll
        for (int s = 0; s < 4; ++s) {
            U4 a0; a0.q = wkA[s];
            U4 a1; a1.q = wkB[s];
            U4 xb; xb.q = xq[s];
            uA = __builtin_amdgcn_mfma_f32_16x16x32_bf16(a0.v, xb.v, uA, 0, 0, 0);
            uB = __builtin_amdgcn_mfma_f32_16x16x32_bf16(a1.v, xb.v, uB, 0, 0, 0);
        }

        // usum exchange via per-wave LDS (replaces 8 bpermutes; bit-identical f32)
        *reinterpret_cast<float4*>(usA + 4 * q) = make_float4(uA[0], uA[1], uA[2], uA[3]);
        *reinterpret_cast<float4*>(usB + 4 * q) = make_float4(uB[0], uB[1], uB[2], uB[3]);
        const float4 eA0 = *reinterpret_cast<const float4*>(usA + zo);
        const float4 eA1 = *reinterpret_cast<const float4*>(usA + zo + 4);
        const float4 eB0 = *reinterpret_cast<const float4*>(usB + zo);
        const float4 eB1 = *reinterpret_cast<const float4*>(usB + zo + 4);
        U4 ubA, ubB;
        ubA.q.x = cvtpk(eA0.x, eA0.y); ubA.q.y = cvtpk(eA0.z, eA0.w);
        ubA.q.z = cvtpk(eA1.x, eA1.y); ubA.q.w = cvtpk(eA1.z, eA1.w);
        ubB.q.x = cvtpk(eB0.x, eB0.y); ubB.q.y = cvtpk(eB0.z, eB0.w);
        ubB.q.z = cvtpk(eB1.x, eB1.y); ubB.q.w = cvtpk(eB1.z, eB1.w);

        const uint4* pv0 = Wp + 8192 + n0 * 512 + lane;
        const uint4* pv1 = Wp + 8192 + n1 * 512 + lane;
        #pragma unroll
        for (int m = 0; m < 8; ++m) {
            U4 a0; a0.q = pv0[m * 64];
            U4 a1; a1.q = pv1[m * 64];
            f32x4 v0 = __builtin_amdgcn_mfma_f32_16x16x32_bf16(a0.v, ubA.v, zero4, 0, 0, 0);
            f32x4 v1 = __builtin_amdgcn_mfma_f32_16x16x32_bf16(a1.v, ubB.v, zero4, 0, 0, 0);
            float p0 = v0[0] * x1[m].x;
            float p1 = v1[0] * x1[m].x;
            p0 = fmaf(v0[1], x1[m].y, p0);  p1 = fmaf(v1[1], x1[m].y, p1);
            p0 = fmaf(v0[2], x1[m].z, p0);  p1 = fmaf(v1[2], x1[m].z, p1);
            p0 = fmaf(v0[3], x1[m].w, p0);  p1 = fmaf(v1[3], x1[m].w, p1);
            p0 += __shfl_xor(p0, 16);       // join the two i-halves (q^1)
            p1 += __shfl_xor(p1, 16);
            if (!(q & 1)) {
                sL[b16 * SLS + n0 * 16 + 2 * m + (q >> 1)] = p0;
                sL[b16 * SLS + n1 * 16 + 2 * m + (q >> 1)] = p1;
            }
        }
    }
    __syncthreads();

    // ---------------- softmax over n (+ bias), one (b,j) per thread (VERIFIED) ----------------
    if (t < 256) {
        const int sb = t >> 4, sj = t & 15;
        float l[32];
        #pragma unroll
        for (int n = 0; n < 32; ++n) l[n] = sL[sb * SLS + n * 16 + sj];
        float m = l[0];
        #pragma unroll
        for (int n = 1; n < 32; ++n) m = fmaxf(m, l[n]);
        float Z = 0.f;
        #pragma unroll
        for (int n = 0; n < 32; ++n) { l[n] = __expf(l[n] - m); Z += l[n]; }
        const float inv = 1.0f / Z;
        #pragma unroll
        for (int n = 0; n < 32; ++n)
            sL[sb * SLS + n * 16 + sj] = fmaf(l[n], inv, sBias[n * 16 + sj]);
    }
    __syncthreads();

    // ---------------- pass 2: c-folded B operand, 2 n in flight ----------------
    #pragma unroll 1
    for (int pr = 0; pr < 2; ++pr) {
        const int n0 = wv * 4 + 2 * pr, n1 = n0 + 1;
        const uint4* pw0 = Wp + n0 * 256 + lane;
        const uint4* pw1 = Wp + n1 * 256 + lane;
        uint4 wkA[4], wkB[4];
        wkA[0] = pw0[0]; wkA[1] = pw0[64]; wkA[2] = pw0[128]; wkA[3] = pw0[192];
        wkB[0] = pw1[0]; wkB[1] = pw1[64]; wkB[2] = pw1[128]; wkB[3] = pw1[192];

        float cA[4], cB[4];
        #pragma unroll
        for (int s = 0; s < 4; ++s) {
            cA[s] = sL[b16 * SLS + n0 * 16 + 4 * s + q];   // c[b16][n0][j=4s+q]
            cB[s] = sL[b16 * SLS + n1 * 16 + 4 * s + q];
        }

        f32x4 sA = zero4, sB = zero4;
        #pragma unroll
        for (int s = 0; s < 4; ++s) {
            const uint4 xv = xq[s];
            U4 yA, yB;
            yA.q.x = cvtpk(cA[s] * __uint_as_float(xv.x << 16), cA[s] * __uint_as_float(xv.x & 0xffff0000u));
            yA.q.y = cvtpk(cA[s] * __uint_as_float(xv.y << 16), cA[s] * __uint_as_float(xv.y & 0xffff0000u));
            yA.q.z = cvtpk(cA[s] * __uint_as_float(xv.z << 16), cA[s] * __uint_as_float(xv.z & 0xffff0000u));
            yA.q.w = cvtpk(cA[s] * __uint_as_float(xv.w << 16), cA[s] * __uint_as_float(xv.w & 0xffff0000u));
            yB.q.x = cvtpk(cB[s] * __uint_as_float(xv.x << 16), cB[s] * __uint_as_float(xv.x & 0xffff0000u));
            yB.q.y = cvtpk(cB[s] * __uint_as_float(xv.y << 16), cB[s] * __uint_as_float(xv.y & 0xffff0000u));
            yB.q.z = cvtpk(cB[s] * __uint_as_float(xv.z << 16), cB[s] * __uint_as_float(xv.z & 0xffff0000u));
            yB.q.w = cvtpk(cB[s] * __uint_as_float(xv.w << 16), cB[s] * __uint_as_float(xv.w & 0xffff0000u));
            U4 a0; a0.q = wkA[s];
            U4 a1; a1.q = wkB[s];
            sA = __builtin_amdgcn_mfma_f32_16x16x32_bf16(a0.v, yA.v, sA, 0, 0, 0);
            sB = __builtin_amdgcn_mfma_f32_16x16x32_bf16(a1.v, yB.v, sB, 0, 0, 0);
        }
        // lane (b16, q) -> Out[bb+b16][n][4q .. 4q+3]  (VERIFIED epilogue)
        float4* op0 = reinterpret_cast<float4*>(Out + (bb + b16) * 512 + n0 * 16 + q * 4);
        float4* op1 = reinterpret_cast<float4*>(Out + (bb + b16) * 512 + n1 * 16 + q * 4);
        *op0 = make_float4(sA[0], sA[1], sA[2], sA[3]);
        *op1 = make_float4(sB[0], sB[1], sB[2], sB[3]);
    }
}

extern "C" void kernel_launch(void* const* d_in, const int* in_sizes, int n_in,
                              void* d_out, int out_size, void* d_ws, size_t ws_size,
                              hipStream_t stream) {
    const float* X  = (const float*)d_in[0];   // (16384, 16, 8) fp32
    const float* W  = (const float*)d_in[1];   // (32, 16, 8, 16) fp32
    const float* Bi = (const float*)d_in[2];   // (32, 16, 1) fp32
    float* Out = (float*)d_out;                // (16384, 32, 16) fp32

    uint4* Wp = (uint4*)d_ws;                  // 384 KiB packed fragments (Wk + Wv)
    prepack<<<96, 256, 0, stream>>>(W, Wp);
    caps<<<B_TOT / TBB, NTH, 0, stream>>>(X, Wp, Bi, Out);
}